// Round 3
// baseline (16997.913 us; speedup 1.0000x reference)
//
#include <hip/hip_runtime.h>

#define NROWS_TOTAL 65536
#define DDIM 512
#define KCODES 1024
#define LLEV 4
#define ROWS 32
#define KT 512
#define CODES_OFF ((size_t)NROWS_TOTAL * DDIM)

typedef __attribute__((address_space(1))) const unsigned int glb_u32_t;
typedef __attribute__((address_space(3))) unsigned int lds_u32_t;

__device__ __forceinline__ void gload_lds16(const float* g, float* l) {
  __builtin_amdgcn_global_load_lds((glb_u32_t*)g, (lds_u32_t*)l, 16, 0, 0);
}

// ---------------- codebook squared norms ----------------
__global__ void csq_kernel(const float* __restrict__ cb, float* __restrict__ csq) {
  int row  = blockIdx.x * 4 + (threadIdx.x >> 6);
  int lane = threadIdx.x & 63;
  const float* p = cb + (size_t)row * DDIM;
  float s = 0.f;
#pragma unroll
  for (int i = 0; i < 8; ++i) { float v = p[lane + 64 * i]; s = fmaf(v, v, s); }
#pragma unroll
  for (int off = 32; off > 0; off >>= 1) s += __shfl_down(s, off, 64);
  if (lane == 0) csq[row] = s;
}

// ---------------- codebook transpose: cbT[l][d][k] ----------------
__global__ void transpose_kernel(const float* __restrict__ cb, float* __restrict__ cbT) {
  __shared__ float t[64][65];
  int l  = blockIdx.z;
  int kb = blockIdx.x * 64;
  int db = blockIdx.y * 64;
  int tid = threadIdx.x;
  {
    int kr = tid >> 2, dq = (tid & 3) * 16;
    const float* src = cb + ((size_t)(l * KCODES + kb + kr) * DDIM) + db + dq;
#pragma unroll
    for (int i = 0; i < 4; ++i) {
      float4 v = *(const float4*)(src + 4 * i);
      t[kr][dq + 4 * i + 0] = v.x; t[kr][dq + 4 * i + 1] = v.y;
      t[kr][dq + 4 * i + 2] = v.z; t[kr][dq + 4 * i + 3] = v.w;
    }
  }
  __syncthreads();
  {
    int dr = tid >> 2, kq = (tid & 3) * 16;
    float* dst = cbT + ((size_t)(l * DDIM + db + dr) * KCODES) + kb + kq;
#pragma unroll
    for (int i = 0; i < 4; ++i) {
      float4 v = make_float4(t[kq + 4 * i + 0][dr], t[kq + 4 * i + 1][dr],
                             t[kq + 4 * i + 2][dr], t[kq + 4 * i + 3][dr]);
      *(float4*)(dst + 4 * i) = v;
    }
  }
}

// ---------------- v3: 16x8 tile, residual in global scratch, 64 barriers/level ----------------
__launch_bounds__(256, 2)
__global__ void rq_v3(const float* __restrict__ x, const float* __restrict__ cb,
                      const float* __restrict__ csq, const float* __restrict__ cbT,
                      float* __restrict__ rb, float* __restrict__ out) {
  __shared__ float ls_cb[2][8 * KCODES];   // 64 KB: chunk = 8 d-rows x 1024 k
  __shared__ float ls_r[2][ROWS * 8];      // 2 x 1 KB DMA dest (contiguous, no pad)
  __shared__ float ls_rsqp[ROWS * 8];
  __shared__ float ls_rsq[ROWS];
  __shared__ float ls_bv[2][2][16];
  __shared__ int   ls_bi[2][2][16];
  __shared__ int   ls_idx[ROWS];

  const int tid  = threadIdx.x;
  const int wv   = tid >> 6;
  const int lane = tid & 63;
  const int rgrp = wv >> 1;       // rows rgrp*16 .. +15
  const int kgrp = wv & 1;        // k   kgrp*512 ..
  const int own_row = tid >> 3;   // update ownership: 32 rows x 8 threads
  const int own_d0  = (tid & 7) * 64;
  const int rowbase = blockIdx.x * ROWS;

  // ---- rsq of level-0 residual (= x); same summation shape as update phase ----
  {
    const float4* xp = (const float4*)(x + (size_t)(rowbase + own_row) * DDIM + own_d0);
    float p = 0.f;
#pragma unroll
    for (int i = 0; i < 16; ++i) {
      float4 v = xp[i];
      p = fmaf(v.x, v.x, p); p = fmaf(v.y, v.y, p);
      p = fmaf(v.z, v.z, p); p = fmaf(v.w, v.w, p);
    }
    ls_rsqp[own_row * 8 + (tid & 7)] = p;
  }
  __syncthreads();
  if (tid < ROWS) {
    float s = 0.f;
#pragma unroll
    for (int i = 0; i < 8; ++i) s += ls_rsqp[tid * 8 + i];
    ls_rsq[tid] = s;
  }
  // first read of ls_rsq is after the j-loop's barriers

  for (int l = 0; l < LLEV; ++l) {
    const float* rsrc = (l == 0) ? x : rb;
    const float* cbTl = cbT + (size_t)l * DDIM * KCODES;

    auto issue = [&](int j, int b) {
      // cb chunk: each wave stages its 256-float k-slice of all 8 d-rows
      const float* g = cbTl + (size_t)(j * 8) * KCODES + wv * 256 + lane * 4;
      float* ld = &ls_cb[b][wv * 256 + lane * 4];
#pragma unroll
      for (int s = 0; s < 8; ++s)
        gload_lds16(g + (size_t)s * KCODES, ld + s * KCODES);
      // r chunk: 32 rows x 8 d = 1 KB, wave 0 only (lds = base + lane*16)
      if (tid < 64) {
        int row = tid >> 1, dh = tid & 1;
        gload_lds16(rsrc + (size_t)(rowbase + row) * DDIM + j * 8 + dh * 4,
                    &ls_r[b][tid * 4]);
      }
    };

    issue(0, 0);

    float acc[16][8];
#pragma unroll
    for (int r = 0; r < 16; ++r)
#pragma unroll
      for (int c = 0; c < 8; ++c) acc[r][c] = 0.f;

    for (int j = 0; j < 64; ++j) {
      const int buf = j & 1;
      __syncthreads();                 // DMA(j) complete; buf^1 free
      if (j < 63) issue(j + 1, buf ^ 1);

      const float* cbb = &ls_cb[buf][(size_t)kgrp * 512 + 4 * lane];
      const float* rbv = &ls_r[buf][rgrp * 16 * 8];
#pragma unroll
      for (int dd = 0; dd < 8; dd += 2) {
        float2 rv[16];
#pragma unroll
        for (int r = 0; r < 16; ++r)
          rv[r] = *(const float2*)&rbv[r * 8 + dd];   // wave-uniform broadcast
#pragma unroll
        for (int t = 0; t < 2; ++t) {
          float4 c0 = *(const float4*)&cbb[(dd + t) * KCODES];
          float4 c1 = *(const float4*)&cbb[(dd + t) * KCODES + 256];
#pragma unroll
          for (int r = 0; r < 16; ++r) {
            float rs = (t == 0) ? rv[r].x : rv[r].y;
            acc[r][0] = fmaf(rs, c0.x, acc[r][0]);
            acc[r][1] = fmaf(rs, c0.y, acc[r][1]);
            acc[r][2] = fmaf(rs, c0.z, acc[r][2]);
            acc[r][3] = fmaf(rs, c0.w, acc[r][3]);
            acc[r][4] = fmaf(rs, c1.x, acc[r][4]);
            acc[r][5] = fmaf(rs, c1.y, acc[r][5]);
            acc[r][6] = fmaf(rs, c1.z, acc[r][6]);
            acc[r][7] = fmaf(rs, c1.w, acc[r][7]);
          }
        }
      }
    }

    // ---- score + argmin:  s = (rsq + csq) - 2*dot  (T=1), lowest-index ties ----
    {
      float4 cs0 = *(const float4*)(csq + l * KCODES + kgrp * 512 + 4 * lane);
      float4 cs1 = *(const float4*)(csq + l * KCODES + kgrp * 512 + 256 + 4 * lane);
      const int kb0 = kgrp * 512 + 4 * lane;
#pragma unroll
      for (int r = 0; r < 16; ++r) {
        float rq = ls_rsq[rgrp * 16 + r];
        float v = 3.4e38f; int idx = 0; float sc;
        sc = (rq + cs0.x) - 2.0f * acc[r][0]; if (sc < v) { v = sc; idx = kb0 + 0; }
        sc = (rq + cs0.y) - 2.0f * acc[r][1]; if (sc < v) { v = sc; idx = kb0 + 1; }
        sc = (rq + cs0.z) - 2.0f * acc[r][2]; if (sc < v) { v = sc; idx = kb0 + 2; }
        sc = (rq + cs0.w) - 2.0f * acc[r][3]; if (sc < v) { v = sc; idx = kb0 + 3; }
        sc = (rq + cs1.x) - 2.0f * acc[r][4]; if (sc < v) { v = sc; idx = kb0 + 256; }
        sc = (rq + cs1.y) - 2.0f * acc[r][5]; if (sc < v) { v = sc; idx = kb0 + 257; }
        sc = (rq + cs1.z) - 2.0f * acc[r][6]; if (sc < v) { v = sc; idx = kb0 + 258; }
        sc = (rq + cs1.w) - 2.0f * acc[r][7]; if (sc < v) { v = sc; idx = kb0 + 259; }
#pragma unroll
        for (int off = 32; off > 0; off >>= 1) {
          float ov = __shfl_xor(v, off, 64);
          int   oi = __shfl_xor(idx, off, 64);
          if (ov < v || (ov == v && oi < idx)) { v = ov; idx = oi; }
        }
        if (lane == 0) { ls_bv[rgrp][kgrp][r] = v; ls_bi[rgrp][kgrp][r] = idx; }
      }
    }
    __syncthreads();
    if (tid < ROWS) {
      int rg2 = tid >> 4, rr = tid & 15;
      float v0 = ls_bv[rg2][0][rr]; int i0 = ls_bi[rg2][0][rr];
      float v1 = ls_bv[rg2][1][rr]; int i1 = ls_bi[rg2][1][rr];
      int bi = (v1 < v0) ? i1 : i0;        // tie -> kgrp 0 (lower k)
      ls_idx[tid] = bi;
      out[CODES_OFF + (size_t)(rowbase + tid) * LLEV + l] = (float)bi;
    }
    __syncthreads();

    // ---- residual update (global scratch, in-place rows) ----
    {
      int idx = ls_idx[own_row];
      const float4* cp = (const float4*)(cb + ((size_t)l * KCODES + idx) * DDIM + own_d0);
      const float4* rp = (const float4*)(rsrc + (size_t)(rowbase + own_row) * DDIM + own_d0);
      if (l < LLEV - 1) {
        float4* wp = (float4*)(rb + (size_t)(rowbase + own_row) * DDIM + own_d0);
        float p = 0.f;
#pragma unroll
        for (int i = 0; i < 16; ++i) {
          float4 rv = rp[i], cv = cp[i];
          float4 n = make_float4(rv.x - cv.x, rv.y - cv.y, rv.z - cv.z, rv.w - cv.w);
          wp[i] = n;
          p = fmaf(n.x, n.x, p); p = fmaf(n.y, n.y, p);
          p = fmaf(n.z, n.z, p); p = fmaf(n.w, n.w, p);
        }
        ls_rsqp[own_row * 8 + (tid & 7)] = p;
        __syncthreads();               // drains rb stores before next level's r-DMA
        if (tid < ROWS) {
          float s = 0.f;
#pragma unroll
          for (int i = 0; i < 8; ++i) s += ls_rsqp[tid * 8 + i];
          ls_rsq[tid] = s;             // consumed after next level's j-loop barriers
        }
      } else {
        const float4* xp = (const float4*)(x + (size_t)(rowbase + own_row) * DDIM + own_d0);
        float4* qp = (float4*)(out + (size_t)(rowbase + own_row) * DDIM + own_d0);
#pragma unroll
        for (int i = 0; i < 16; ++i) {
          float4 rv = rp[i], cv = cp[i], xv = xp[i];
          float4 n = make_float4(rv.x - cv.x, rv.y - cv.y, rv.z - cv.z, rv.w - cv.w);
          qp[i] = make_float4(xv.x - n.x, xv.y - n.y, xv.z - n.z, xv.w - n.w);
        }
      }
    }
  }
}

// ---------------- fallback: R2 kernel (register-resident residual) ----------------
__launch_bounds__(256, 2)
__global__ void rq_fast(const float* __restrict__ x, const float* __restrict__ cb,
                        const float* __restrict__ csq, const float* __restrict__ cbT,
                        float* __restrict__ out) {
  __shared__ float ls_cb[2][8 * KT];
  __shared__ float ls_r[2][ROWS * 12];
  __shared__ float ls_rsqp[ROWS * 8];
  __shared__ float ls_rsq[ROWS];

  const int tid = threadIdx.x;
  const int rg  = tid >> 6;
  const int kg  = tid & 63;
  const int own_row = tid >> 3;
  const int own_d0  = (tid & 7) * 64;
  const int rowbase = blockIdx.x * ROWS;

  float rres[64];
  {
    const float4* xp = (const float4*)(x + (size_t)(rowbase + own_row) * DDIM + own_d0);
#pragma unroll
    for (int i = 0; i < 16; ++i) {
      float4 v = xp[i];
      rres[4*i] = v.x; rres[4*i+1] = v.y; rres[4*i+2] = v.z; rres[4*i+3] = v.w;
    }
  }

  auto issue_chunk = [&](int l, int j, int buf) {
    int kt = j >> 6, dc = j & 63;
    const float* gbase = cbT + ((size_t)(l * DDIM + dc * 8) * KCODES) + kt * KT + kg * 4;
    float* lbase = &ls_cb[buf][kg * 4];
#pragma unroll
    for (int s = 0; s < 4; ++s) {
      int dloc = rg * 2 + (s >> 1);
      int half = s & 1;
      gload_lds16(gbase + (size_t)dloc * KCODES + half * 256,
                  lbase + dloc * KT + half * 256);
    }
  };

#define WRQ(PAR, Q)                                                              \
  {                                                                              \
    float* dp = &ls_r[PAR][own_row * 12];                                        \
    *(float4*)(dp + 0) = make_float4(rres[(Q)*8+0], rres[(Q)*8+1],               \
                                     rres[(Q)*8+2], rres[(Q)*8+3]);              \
    *(float4*)(dp + 4) = make_float4(rres[(Q)*8+4], rres[(Q)*8+5],               \
                                     rres[(Q)*8+6], rres[(Q)*8+7]);              \
  }

  auto write_lsr = [&](int dcn, int par) {
    if ((tid & 7) == (dcn >> 3)) {
      switch (dcn & 7) {
        case 0: WRQ(par, 0); break;
        case 1: WRQ(par, 1); break;
        case 2: WRQ(par, 2); break;
        case 3: WRQ(par, 3); break;
        case 4: WRQ(par, 4); break;
        case 5: WRQ(par, 5); break;
        case 6: WRQ(par, 6); break;
        case 7: WRQ(par, 7); break;
      }
    }
  };

  issue_chunk(0, 0, 0);
  write_lsr(0, 0);

  for (int l = 0; l < LLEV; ++l) {
    {
      float p = 0.f;
#pragma unroll
      for (int i = 0; i < 64; ++i) p = fmaf(rres[i], rres[i], p);
      ls_rsqp[own_row * 8 + (tid & 7)] = p;
    }
    __syncthreads();
    if (tid < ROWS) {
      float s = 0.f;
#pragma unroll
      for (int i = 0; i < 8; ++i) s += ls_rsqp[tid * 8 + i];
      ls_rsq[tid] = s;
    }
    __syncthreads();
    float rsqv[8];
#pragma unroll
    for (int r = 0; r < 8; ++r) rsqv[r] = ls_rsq[rg * 8 + r];

    float mv[8]; int mi[8];
#pragma unroll
    for (int r = 0; r < 8; ++r) { mv[r] = 3.4e38f; mi[r] = 0; }

    float acc[8][8];
    float4 cs0, cs1;

    for (int j = 0; j < 128; ++j) {
      const int kt  = j >> 6;
      const int buf = j & 1;
      __syncthreads();

      if ((j & 63) == 0) {
        cs0 = *(const float4*)(csq + l * KCODES + kt * KT + 4 * kg);
        cs1 = *(const float4*)(csq + l * KCODES + kt * KT + 256 + 4 * kg);
#pragma unroll
        for (int r = 0; r < 8; ++r)
#pragma unroll
          for (int c = 0; c < 8; ++c) acc[r][c] = 0.f;
      }

      if (!(l == LLEV - 1 && j == 127)) {
        int nl = (j == 127) ? l + 1 : l;
        int nj = (j == 127) ? 0 : j + 1;
        issue_chunk(nl, nj, buf ^ 1);
      }
      if (j < 127) write_lsr((j + 1) & 63, (j + 1) & 1);

      const float* cbb = &ls_cb[buf][0];
      const float* rb  = &ls_r[buf][0];
#pragma unroll
      for (int ds4 = 0; ds4 < 2; ++ds4) {
        float rvf[4][8];
#pragma unroll
        for (int r = 0; r < 8; ++r) {
          float4 t = *(const float4*)&rb[(rg * 8 + r) * 12 + ds4 * 4];
          rvf[0][r] = t.x; rvf[1][r] = t.y; rvf[2][r] = t.z; rvf[3][r] = t.w;
        }
#pragma unroll
        for (int jj = 0; jj < 4; ++jj) {
          float4 cv0 = *(const float4*)&cbb[(ds4 * 4 + jj) * KT + 4 * kg];
          float4 cv1 = *(const float4*)&cbb[(ds4 * 4 + jj) * KT + 256 + 4 * kg];
#pragma unroll
          for (int r = 0; r < 8; ++r) {
            float rv = rvf[jj][r];
            acc[r][0] = fmaf(rv, cv0.x, acc[r][0]);
            acc[r][1] = fmaf(rv, cv0.y, acc[r][1]);
            acc[r][2] = fmaf(rv, cv0.z, acc[r][2]);
            acc[r][3] = fmaf(rv, cv0.w, acc[r][3]);
            acc[r][4] = fmaf(rv, cv1.x, acc[r][4]);
            acc[r][5] = fmaf(rv, cv1.y, acc[r][5]);
            acc[r][6] = fmaf(rv, cv1.z, acc[r][6]);
            acc[r][7] = fmaf(rv, cv1.w, acc[r][7]);
          }
        }
      }

      if ((j & 63) == 63) {
#pragma unroll
        for (int g = 0; g < 2; ++g) {
          float4 cs = g ? cs1 : cs0;
#pragma unroll
          for (int c = 0; c < 4; ++c) {
            int k = kt * KT + g * 256 + 4 * kg + c;
            float csv = (c == 0) ? cs.x : (c == 1) ? cs.y : (c == 2) ? cs.z : cs.w;
#pragma unroll
            for (int r = 0; r < 8; ++r) {
              float s = (rsqv[r] + csv) - 2.0f * acc[r][g * 4 + c];
              if (s < mv[r]) { mv[r] = s; mi[r] = k; }
            }
          }
        }
      }
    }

#pragma unroll
    for (int r = 0; r < 8; ++r) {
      float v = mv[r]; int i = mi[r];
#pragma unroll
      for (int off = 32; off > 0; off >>= 1) {
        float ov = __shfl_xor(v, off, 64);
        int   oi = __shfl_xor(i, off, 64);
        if (ov < v || (ov == v && oi < i)) { v = ov; i = oi; }
      }
      mv[r] = v; mi[r] = i;
      if (kg == r)
        out[CODES_OFF + (size_t)(rowbase + rg * 8 + r) * LLEV + l] = (float)i;
    }

    {
      int r8 = (tid >> 3) & 7;
      int idx = mi[0];
#pragma unroll
      for (int r = 1; r < 8; ++r) if (r8 == r) idx = mi[r];
      const float4* cp = (const float4*)(cb + ((size_t)l * KCODES + idx) * DDIM + own_d0);
#pragma unroll
      for (int i = 0; i < 16; ++i) {
        float4 v = cp[i];
        rres[4*i]   -= v.x; rres[4*i+1] -= v.y;
        rres[4*i+2] -= v.z; rres[4*i+3] -= v.w;
      }
    }
    if (l < LLEV - 1) write_lsr(0, 0);
  }

  {
    const float4* xp = (const float4*)(x + (size_t)(rowbase + own_row) * DDIM + own_d0);
    float4* op = (float4*)(out + (size_t)(rowbase + own_row) * DDIM + own_d0);
#pragma unroll
    for (int i = 0; i < 16; ++i) {
      float4 v = xp[i];
      op[i] = make_float4(v.x - rres[4*i],   v.y - rres[4*i+1],
                          v.z - rres[4*i+2], v.w - rres[4*i+3]);
    }
  }
}

extern "C" void kernel_launch(void* const* d_in, const int* in_sizes, int n_in,
                              void* d_out, int out_size, void* d_ws, size_t ws_size,
                              hipStream_t stream) {
  const float* x  = (const float*)d_in[0];
  const float* cb = (const float*)d_in[1];
  float* out = (float*)d_out;

  float* csq = (float*)d_ws;                              // [L*K]
  float* cbT = (float*)d_ws + 4096;                       // [L][D][K]
  float* rb  = cbT + (size_t)LLEV * DDIM * KCODES;        // [N][D] residual scratch

  const size_t need_mid  = (size_t)(4096 + (size_t)LLEV * DDIM * KCODES) * sizeof(float);
  const size_t need_full = need_mid + (size_t)NROWS_TOTAL * DDIM * sizeof(float);

  csq_kernel<<<dim3((LLEV * KCODES) / 4), dim3(256), 0, stream>>>(cb, csq);
  if (ws_size >= need_full) {
    transpose_kernel<<<dim3(KCODES / 64, DDIM / 64, LLEV), dim3(256), 0, stream>>>(cb, cbT);
    rq_v3<<<dim3(NROWS_TOTAL / ROWS), dim3(256), 0, stream>>>(x, cb, csq, cbT, rb, out);
  } else {
    transpose_kernel<<<dim3(KCODES / 64, DDIM / 64, LLEV), dim3(256), 0, stream>>>(cb, cbT);
    rq_fast<<<dim3(NROWS_TOTAL / ROWS), dim3(256), 0, stream>>>(x, cb, csq, cbT, out);
  }
}